// Round 4
// baseline (4010.665 us; speedup 1.0000x reference)
//
#include <hip/hip_runtime.h>
#include <math.h>

#define EPS 1e-5f

// ---------------------------------------------------------------------------
// Shapes: B=512, N=64, N_AFEAT=128, NGC1=300, NGC2=600, DEN1=512, DEN2=256
// ws layout (floats):
//   A1    : [5][512][64][64]  = 10,485,760
//   A2    : [5][512][64][64]  = 10,485,760
//   x1    : [512][64][300]    =  9,830,400
//   rb    : [512][64]         =     32,768
//   molfp : [512][600]        =    307,200
// total ~118.8 MiB
// ---------------------------------------------------------------------------

__device__ __forceinline__ float wred_max(float v){
  #pragma unroll
  for (int off = 32; off >= 1; off >>= 1) v = fmaxf(v, __shfl_xor(v, off, 64));
  return v;
}
__device__ __forceinline__ float wred_sum(float v){
  #pragma unroll
  for (int off = 32; off >= 1; off >>= 1) v += __shfl_xor(v, off, 64);
  return v;
}

// ---------------------------------------------------------------------------
// K1: attention maps for both layers. One wave per (b,n) row, lane = m.
// Memory-bound: reads all relation tensors once (~460 MB total traffic).
// ---------------------------------------------------------------------------
__global__ __launch_bounds__(256) void k_attn(
    const float* __restrict__ adjs,
    const float* __restrict__ bfts,  const float* __restrict__ order,
    const float* __restrict__ arom,  const float* __restrict__ conj,
    const float* __restrict__ ring,
    const float* __restrict__ w10, const float* __restrict__ w11,
    const float* __restrict__ w12, const float* __restrict__ w13,
    const float* __restrict__ w14,
    const float* __restrict__ w20, const float* __restrict__ w21,
    const float* __restrict__ w22, const float* __restrict__ w23,
    const float* __restrict__ w24,
    float* __restrict__ A1, float* __restrict__ A2, float* __restrict__ rbw)
{
  const int lane = threadIdx.x & 63;
  const int w    = threadIdx.x >> 6;
  const int row  = blockIdx.x * 4 + w;       // = b*64 + n
  const int b    = row >> 6;
  const int n    = row & 63;

  const float adj  = adjs[(size_t)row * 64 + lane];
  const float mask = (1.0f - adj) * -1e9f;
  const float rbv  = wred_max(adj);          // mask_blank / mask2 (rowmax of adj)
  if (lane == 0) rbw[row] = rbv;

  const float* fps[5] = {bfts, order, arom, conj, ring};
  const float* w1s[5] = {w10, w11, w12, w13, w14};
  const float* w2s[5] = {w20, w21, w22, w23, w24};
  const int    Cs[5]  = {30, 5, 3, 3, 3};

  for (int i = 0; i < 5; ++i) {
    const float* fp = fps[i];
    const int C = Cs[i];
    float s1 = 0.f, s2 = 0.f;
    for (int c = 0; c < C; ++c) {
      float f = fp[(((size_t)b * C + c) * 64 + n) * 64 + lane];
      s1 += f * w1s[i][c];
      s2 += f * w2s[i][c];
    }
    // layer-1 attention
    float z = s1 + mask;
    float M = wred_max(z);
    float e = __expf(z - M);
    float S = wred_sum(e);
    float A = (e / S) * rbv;
    if (i == 4) {                            // ring view: softmax applied twice
      float z2 = A + mask;
      float M2 = wred_max(z2);
      float e2 = __expf(z2 - M2);
      float S2 = wred_sum(e2);
      A = (e2 / S2) * rbv;
    }
    const size_t oi = (((size_t)i * 512 + b) * 64 + n) * 64 + lane;
    A1[oi] = A;
    // layer-2 attention
    float zb = s2 + mask;
    float Mb = wred_max(zb);
    float eb = __expf(zb - Mb);
    float Sb = wred_sum(eb);
    A2[oi] = (eb / Sb) * rbv;
  }
}

// ---------------------------------------------------------------------------
// K2: layer 1.  Per block: one molecule b.
//   T1 = A1[i,b] (64x64) @ afms[b] (64x128)   -> LDS (pitch 133, conflict-free cols)
//   H  = T1 @ gc1_W[i] (128x300), + bias, BN, ReLU, *rb, *ave1 -> accumulate x1
//   H phase: wave owns 75 g's (3 chunks of 25); k chunked by 4 with explicit
//   register double-buffer of the T-column reads (hides ~120cy LDS latency).
// ---------------------------------------------------------------------------
__global__ __launch_bounds__(256, 2) void k_layer1(
    const float* __restrict__ afms, const float* __restrict__ A1,
    const float* __restrict__ gc1W, const float* __restrict__ gc1b,
    const float* __restrict__ bn1p, const float* __restrict__ ave1,
    const float* __restrict__ rbw,  float* __restrict__ x1)
{
  __shared__ float T1s[64 * 133];            // 34,048 B
  const int lane = threadIdx.x & 63;
  const int w    = __builtin_amdgcn_readfirstlane(threadIdx.x >> 6);
  const int b    = blockIdx.x;
  const float rbv = rbw[b * 64 + lane];
  const float* Xp = afms + (size_t)b * 64 * 128;

  for (int i = 0; i < 5; ++i) {
    __syncthreads();                         // protect T1s from previous view readers
    // ---- T1 phase: lane = f (and f+64), wave w owns rows n = w*16..w*16+15
    float t1a[16], t1b[16];
    #pragma unroll
    for (int j = 0; j < 16; ++j) { t1a[j] = 0.f; t1b[j] = 0.f; }
    const float* Ap = A1 + (((size_t)i * 512 + b) * 64) * 64;
    for (int m4 = 0; m4 < 16; ++m4) {
      float xa[4], xb[4];
      #pragma unroll
      for (int t = 0; t < 4; ++t) {
        xa[t] = Xp[(m4 * 4 + t) * 128 + lane];
        xb[t] = Xp[(m4 * 4 + t) * 128 + lane + 64];
      }
      #pragma unroll
      for (int j = 0; j < 16; ++j) {
        const float4 a4 = *reinterpret_cast<const float4*>(Ap + (w * 16 + j) * 64 + m4 * 4);
        t1a[j] += a4.x * xa[0] + a4.y * xa[1] + a4.z * xa[2] + a4.w * xa[3];
        t1b[j] += a4.x * xb[0] + a4.y * xb[1] + a4.z * xb[2] + a4.w * xb[3];
      }
    }
    #pragma unroll
    for (int j = 0; j < 16; ++j) {
      T1s[(w * 16 + j) * 133 + lane]      = t1a[j];
      T1s[(w * 16 + j) * 133 + lane + 64] = t1b[j];
    }
    __syncthreads();
    // ---- H phase: lane = n, wave w owns g = w*75 .. w*75+74 (3 chunks of 25)
    const float* Wp = gc1W + (size_t)i * 128 * 300;
    const float  av = ave1[i];
    for (int c = 0; c < 3; ++c) {
      const int g0 = w * 75 + c * 25;
      float hacc[25];
      #pragma unroll
      for (int jj = 0; jj < 25; ++jj) hacc[jj] = 0.f;
      float tc4[4], tn4[4];
      #pragma unroll
      for (int t = 0; t < 4; ++t) tc4[t] = T1s[lane * 133 + t];
      for (int k0 = 0; k0 < 128; k0 += 4) {
        if (k0 < 124) {
          #pragma unroll
          for (int t = 0; t < 4; ++t) tn4[t] = T1s[lane * 133 + k0 + 4 + t];
        }
        #pragma unroll
        for (int t = 0; t < 4; ++t) {
          const float* wr = Wp + (k0 + t) * 300 + g0;   // wave-uniform -> s_load
          #pragma unroll
          for (int jj = 0; jj < 25; ++jj) hacc[jj] += tc4[t] * wr[jj];
        }
        #pragma unroll
        for (int t = 0; t < 4; ++t) tc4[t] = tn4[t];
      }
      #pragma unroll
      for (int jj = 0; jj < 25; ++jj) {
        const int g = g0 + jj;
        float h     = hacc[jj] + gc1b[i * 300 + g];
        float gamma = bn1p[(i * 4 + 0) * 300 + g];
        float beta  = bn1p[(i * 4 + 1) * 300 + g];
        float mean  = bn1p[(i * 4 + 2) * 300 + g];
        float var   = bn1p[(i * 4 + 3) * 300 + g];
        float v = (h - mean) * (gamma * rsqrtf(var + EPS)) + beta;
        v = fmaxf(v, 0.f) * rbv * av;
        const size_t xi = ((size_t)b * 64 + lane) * 300 + g;
        x1[xi] = (i == 0) ? v : (x1[xi] + v);  // block-exclusive RMW, no race
      }
    }
  }
}

// ---------------------------------------------------------------------------
// K3: layer 2 + MolFP sum.  Per block: one molecule b.
//   T2 = A2[i,b] (64x64) @ x1[b] (64x300) -> LDS (pitch 301, conflict-free cols)
//   H2 = T2 @ gc2_W[i] (300x600), epilogue, then sum over atoms (lanes) -> molfp
//   H2 phase: wave owns 150 g's (5 chunks of 30); k chunked by 4 with explicit
//   register double-buffer of the T-column reads.
// ---------------------------------------------------------------------------
__global__ __launch_bounds__(256, 2) void k_layer2(
    const float* __restrict__ x1,   const float* __restrict__ A2,
    const float* __restrict__ gc2W, const float* __restrict__ gc2b,
    const float* __restrict__ bn2p, const float* __restrict__ ave2,
    const float* __restrict__ rbw,  float* __restrict__ molfp)
{
  extern __shared__ float T2s[];             // 64*301 floats = 77,056 B
  const int lane = threadIdx.x & 63;
  const int w    = __builtin_amdgcn_readfirstlane(threadIdx.x >> 6);
  const int b    = blockIdx.x;
  const float rbv = rbw[b * 64 + lane];
  const float* Xp = x1 + (size_t)b * 64 * 300;

  for (int i = 0; i < 5; ++i) {
    __syncthreads();
    // ---- T2 phase: lane = g within 60-chunk, wave w owns rows n = w*16+j
    const float* Ap = A2 + (((size_t)i * 512 + b) * 64) * 64;
    for (int c = 0; c < 5; ++c) {
      const bool act = lane < 60;
      const int  g   = c * 60 + (act ? lane : 0);
      float acc[16];
      #pragma unroll
      for (int j = 0; j < 16; ++j) acc[j] = 0.f;
      for (int m4 = 0; m4 < 16; ++m4) {
        float xv[4];
        #pragma unroll
        for (int t = 0; t < 4; ++t) xv[t] = Xp[(m4 * 4 + t) * 300 + g];
        #pragma unroll
        for (int j = 0; j < 16; ++j) {
          const float4 a4 = *reinterpret_cast<const float4*>(Ap + (w * 16 + j) * 64 + m4 * 4);
          acc[j] += a4.x * xv[0] + a4.y * xv[1] + a4.z * xv[2] + a4.w * xv[3];
        }
      }
      if (act) {
        #pragma unroll
        for (int j = 0; j < 16; ++j) T2s[(w * 16 + j) * 301 + g] = acc[j];
      }
    }
    __syncthreads();
    // ---- H2 phase: lane = n, wave w owns g = w*150 .. w*150+149 (5 chunks of 30)
    const float* Wp = gc2W + (size_t)i * 300 * 600;
    const float  av = ave2[i];
    for (int c2 = 0; c2 < 5; ++c2) {
      const int g0 = w * 150 + c2 * 30;
      float hacc[30];
      #pragma unroll
      for (int jj = 0; jj < 30; ++jj) hacc[jj] = 0.f;
      float tc4[4], tn4[4];
      #pragma unroll
      for (int t = 0; t < 4; ++t) tc4[t] = T2s[lane * 301 + t];
      for (int k0 = 0; k0 < 300; k0 += 4) {
        if (k0 < 296) {
          #pragma unroll
          for (int t = 0; t < 4; ++t) tn4[t] = T2s[lane * 301 + k0 + 4 + t];
        }
        #pragma unroll
        for (int t = 0; t < 4; ++t) {
          const float* wr = Wp + (k0 + t) * 600 + g0;   // wave-uniform -> s_load
          #pragma unroll
          for (int jj = 0; jj < 30; ++jj) hacc[jj] += tc4[t] * wr[jj];
        }
        #pragma unroll
        for (int t = 0; t < 4; ++t) tc4[t] = tn4[t];
      }
      #pragma unroll
      for (int jj = 0; jj < 30; ++jj) {
        const int g = g0 + jj;
        float h     = hacc[jj] + gc2b[i * 600 + g];
        float gamma = bn2p[(i * 4 + 0) * 600 + g];
        float beta  = bn2p[(i * 4 + 1) * 600 + g];
        float mean  = bn2p[(i * 4 + 2) * 600 + g];
        float var   = bn2p[(i * 4 + 3) * 600 + g];
        float v = (h - mean) * (gamma * rsqrtf(var + EPS)) + beta;
        v = fmaxf(v, 0.f) * rbv * av;
        float s = wred_sum(v);               // sum over atoms (lanes = n)
        if (lane == 0) {
          const size_t mi = (size_t)b * 600 + g;
          molfp[mi] = (i == 0) ? s : (molfp[mi] + s);  // single writer per (b,g)
        }
      }
    }
  }
}

// ---------------------------------------------------------------------------
// K4: MolFP BN + dense head. 4 molecules per block (W reuse x4), activations
// staged TRANSPOSED in LDS ([k][m], m=0..3) so the GEMV inner loop is
// 1 uniform ds_read_b128 + 1 coalesced global load + 4 v_fmac per k.
// ---------------------------------------------------------------------------
#define BMOL 4
__global__ __launch_bounds__(256) void k_dense(
    const float* __restrict__ molfp, const float* __restrict__ mbn,
    const float* __restrict__ d1W, const float* __restrict__ d1b,
    const float* __restrict__ d2W, const float* __restrict__ d2b,
    const float* __restrict__ d3W, const float* __restrict__ d3b,
    const float* __restrict__ bnd1, const float* __restrict__ bnd2,
    float* __restrict__ out)
{
  __shared__ float v0[600 * BMOL];   // [k][m]
  __shared__ float v1[512 * BMOL];   // [k][m]
  __shared__ float v2[256 * BMOL];   // [k][m]
  const int tid = threadIdx.x;
  const int b0  = blockIdx.x * BMOL;

  // stage BN(molfp) transposed
  for (int idx = tid; idx < 600 * BMOL; idx += 256) {
    const int k = idx >> 2, m = idx & 3;
    float mm = molfp[(size_t)(b0 + m) * 600 + k];
    v0[k * BMOL + m] = (mm - mbn[1200 + k]) *
                       (mbn[k] * rsqrtf(mbn[1800 + k] + EPS)) + mbn[600 + k];
  }
  __syncthreads();

  // dense1: 600 -> 512, BN + ReLU
  for (int o = tid; o < 512; o += 256) {
    float a0 = d1b[o], a1 = a0, a2 = a0, a3 = a0;
    for (int k = 0; k < 600; ++k) {
      const float  wk = d1W[k * 512 + o];
      const float4 v  = *reinterpret_cast<const float4*>(&v0[k * BMOL]);
      a0 += v.x * wk; a1 += v.y * wk; a2 += v.z * wk; a3 += v.w * wk;
    }
    const float sc = bnd1[o] * rsqrtf(bnd1[3 * 512 + o] + EPS);
    const float mn = bnd1[2 * 512 + o], bt = bnd1[512 + o];
    v1[o * BMOL + 0] = fmaxf((a0 - mn) * sc + bt, 0.f);
    v1[o * BMOL + 1] = fmaxf((a1 - mn) * sc + bt, 0.f);
    v1[o * BMOL + 2] = fmaxf((a2 - mn) * sc + bt, 0.f);
    v1[o * BMOL + 3] = fmaxf((a3 - mn) * sc + bt, 0.f);
  }
  __syncthreads();

  // dense2: 512 -> 256, BN + ReLU  (exactly one o per thread)
  {
    const int o = tid;
    float a0 = d2b[o], a1 = a0, a2 = a0, a3 = a0;
    for (int k = 0; k < 512; ++k) {
      const float  wk = d2W[k * 256 + o];
      const float4 v  = *reinterpret_cast<const float4*>(&v1[k * BMOL]);
      a0 += v.x * wk; a1 += v.y * wk; a2 += v.z * wk; a3 += v.w * wk;
    }
    const float sc = bnd2[o] * rsqrtf(bnd2[3 * 256 + o] + EPS);
    const float mn = bnd2[2 * 256 + o], bt = bnd2[256 + o];
    v2[o * BMOL + 0] = fmaxf((a0 - mn) * sc + bt, 0.f);
    v2[o * BMOL + 1] = fmaxf((a1 - mn) * sc + bt, 0.f);
    v2[o * BMOL + 2] = fmaxf((a2 - mn) * sc + bt, 0.f);
    v2[o * BMOL + 3] = fmaxf((a3 - mn) * sc + bt, 0.f);
  }
  __syncthreads();

  // dense3: 256 -> 2 per molecule; wave m handles molecule b0+m
  {
    const int m = tid >> 6, lane = tid & 63;
    #pragma unroll
    for (int c = 0; c < 2; ++c) {
      float acc = 0.f;
      for (int k = lane; k < 256; k += 64) acc += v2[k * BMOL + m] * d3W[k * 2 + c];
      acc = wred_sum(acc);
      if (lane == 0) out[(b0 + m) * 2 + c] = acc + d3b[c];
    }
  }
}

// ---------------------------------------------------------------------------
extern "C" void kernel_launch(void* const* d_in, const int* in_sizes, int n_in,
                              void* d_out, int out_size, void* d_ws, size_t ws_size,
                              hipStream_t stream)
{
  (void)in_sizes; (void)n_in; (void)out_size; (void)ws_size;

  const float* adjs  = (const float*)d_in[0];
  const float* afms  = (const float*)d_in[1];
  const float* bfts  = (const float*)d_in[2];
  const float* order = (const float*)d_in[3];
  const float* arom  = (const float*)d_in[4];
  const float* conj  = (const float*)d_in[5];
  const float* ring  = (const float*)d_in[6];
  const float* aw11  = (const float*)d_in[7];
  const float* aw12  = (const float*)d_in[8];
  const float* aw13  = (const float*)d_in[9];
  const float* aw14  = (const float*)d_in[10];
  const float* aw15  = (const float*)d_in[11];
  const float* aw21  = (const float*)d_in[12];
  const float* aw22  = (const float*)d_in[13];
  const float* aw23  = (const float*)d_in[14];
  const float* aw24  = (const float*)d_in[15];
  const float* aw25  = (const float*)d_in[16];
  const float* gc1W  = (const float*)d_in[17];
  const float* gc1b  = (const float*)d_in[18];
  const float* gc2W  = (const float*)d_in[19];
  const float* gc2b  = (const float*)d_in[20];
  const float* ave1  = (const float*)d_in[21];
  const float* ave2  = (const float*)d_in[22];
  const float* bn1p  = (const float*)d_in[23];
  const float* bn2p  = (const float*)d_in[24];
  const float* mbn   = (const float*)d_in[25];
  const float* d1W   = (const float*)d_in[26];
  const float* d1b   = (const float*)d_in[27];
  const float* d2W   = (const float*)d_in[28];
  const float* d2b   = (const float*)d_in[29];
  const float* d3W   = (const float*)d_in[30];
  const float* d3b   = (const float*)d_in[31];
  const float* bnd1  = (const float*)d_in[32];
  const float* bnd2  = (const float*)d_in[33];

  float* ws    = (float*)d_ws;
  float* A1    = ws;                    // 10,485,760 floats
  float* A2    = A1 + 10485760;         // 10,485,760
  float* x1    = A2 + 10485760;         //  9,830,400
  float* rbw   = x1 + 9830400;          //     32,768
  float* molfp = rbw + 32768;           //    307,200

  k_attn<<<8192, 256, 0, stream>>>(adjs, bfts, order, arom, conj, ring,
                                   aw11, aw12, aw13, aw14, aw15,
                                   aw21, aw22, aw23, aw24, aw25,
                                   A1, A2, rbw);

  k_layer1<<<512, 256, 0, stream>>>(afms, A1, gc1W, gc1b, bn1p, ave1, rbw, x1);

  (void)hipFuncSetAttribute((const void*)k_layer2,
                            hipFuncAttributeMaxDynamicSharedMemorySize,
                            64 * 301 * 4);
  k_layer2<<<512, 256, 64 * 301 * 4, stream>>>(x1, A2, gc2W, gc2b, bn2p, ave2,
                                               rbw, molfp);

  k_dense<<<128, 256, 0, stream>>>(molfp, mbn, d1W, d1b, d2W, d2b, d3W, d3b,
                                   bnd1, bnd2, (float*)d_out);
}